// Round 13
// baseline (192.719 us; speedup 1.0000x reference)
//
#include <hip/hip_runtime.h>
#include <hip/hip_bf16.h>
#include <math.h>

// Problem constants
#define BB 8
#define SS 2048
#define DD 512
#define II 768
#define MT (BB*SS)        // 16384 positions
#define NS 16             // state dim
#define CH 32             // scan chunk length
#define NCB (SS/CH)       // 64 chunks per batch
#define NCHK (MT/CH)      // 512 chunks total
#define NT 1024           // expm table size

typedef __hip_bfloat16 bf16;
typedef __attribute__((ext_vector_type(8))) short bf16x8;
typedef __attribute__((ext_vector_type(4))) float f32x4;

__device__ __forceinline__ float fsigm(float x){
  return __builtin_amdgcn_rcpf(1.f + __expf(-x));          // v_exp + v_rcp
}
__device__ __forceinline__ float fsoftp(float x){
  return (x > 15.f) ? x : __logf(1.f + __expf(x));         // v_exp + v_log
}
__device__ __forceinline__ unsigned short f2bf_bits(float f){
  __hip_bfloat16 h = __float2bfloat16(f);
  return __builtin_bit_cast(unsigned short, h);
}
__device__ __forceinline__ float bfbits2f(short s){
  union { float f; unsigned u; } v;
  v.u = ((unsigned)(unsigned short)s) << 16;
  return v.f;
}
__device__ __forceinline__ void gload16(const bf16* src, void* dst){
  __builtin_amdgcn_global_load_lds((const __attribute__((address_space(1))) void*)src,
                                   (__attribute__((address_space(3))) void*)dst, 16, 0, 0);
}
__device__ __forceinline__ void gload16f(const float* src, void* dst){
  __builtin_amdgcn_global_load_lds((const __attribute__((address_space(1))) void*)src,
                                   (__attribute__((address_space(3))) void*)dst, 16, 0, 0);
}
template<int KDIM>
__device__ __forceinline__ bf16x8 lds_a_frag(const bf16* As, int row, int kseg){
  return *(const bf16x8*)((const char*)As + (size_t)row*(KDIM*2)
                          + (size_t)((kseg ^ (row & 7)) << 4));
}

// ======= prep+etab fused (1 dispatch, was 2): =======
// Blocks 0..NT-1: one expm-table entry each, 256 thr (1 elem/thread, 4x TLP vs
// the old 64-thr kernel). A-powers computed LOCALLY in f64 LDS (192 FMA/thread)
// -> no global Apow buffer, no cross-kernel dependency. All accumulation orders
// replicate the old kernel exactly -> bit-identical Etab/Gtab/dEtab.
// Blocks NT..NT+1599: W_in/W_out cast + Bm hi/lo split + dacc zero.
__global__ __launch_bounds__(256) void prep_etab_kernel(
    const float* __restrict__ W_in, const float* __restrict__ Wout,
    const float* __restrict__ Bm, const float* __restrict__ A,
    bf16* __restrict__ Winbf, bf16* __restrict__ Woutbf,
    bf16* __restrict__ Bmhi, bf16* __restrict__ Bmlo,
    float* __restrict__ dacc,
    float* __restrict__ Etab, float* __restrict__ Gtab, float* __restrict__ dEtab)
{
  const int tid = threadIdx.x;
  if (blockIdx.x < NT){
    __shared__ double Am[256], T0[256], T1[256];
    __shared__ double colsum[16];
    __shared__ float ApL[13*256];       // A^1..A^13 as f32 (13 KB)
    __shared__ float bufE[256], bufG[256];
    __shared__ float sanorm;
    const int i = blockIdx.x;
    const int r = tid>>4, c = tid&15;
    double a = (double)A[tid];
    Am[tid] = a; T0[tid] = a; ApL[tid] = (float)a;
    __syncthreads();
    double *Tc = T0, *Tn = T1;
    for (int k=2;k<=13;k++){
      double s = 0.0;
      #pragma unroll
      for (int j=0;j<16;j++) s += Tc[r*16+j]*Am[j*16+c];
      Tn[tid] = s;
      ApL[(k-1)*256 + tid] = (float)s;
      __syncthreads();
      double* tmp = Tc; Tc = Tn; Tn = tmp;
    }
    if (tid < 16){
      double s = 0.0;
      #pragma unroll
      for (int j=0;j<16;j++) s += fabs(Am[j*16+tid]);
      colsum[tid] = s;
    }
    __syncthreads();
    if (tid == 0){
      double mx = 0.0;
      #pragma unroll
      for (int j=0;j<16;j++) mx = fmax(mx, colsum[j]);
      sanorm = (float)mx;
    }
    __syncthreads();
    const float anorm = sanorm;
    float delta = (3.0f*i)/(float)(NT-1);
    float mxv = delta*anorm;
    int s = 0;
    if (mxv > 2.f){
      s = (int)ceilf(log2f(mxv)) - 1;
      if (s < 0) s = 0;
      if (s > 12) s = 12;
    }
    float dsc = ldexpf(delta, -s);
    const float invk[14]  = {0.f, 1.f, 0.5f, 1.f/3.f, 0.25f, 0.2f, 1.f/6.f, 1.f/7.f,
                             0.125f, 1.f/9.f, 0.1f, 1.f/11.f, 1.f/12.f, 1.f/13.f};
    float e = (r==c) ? 1.f : 0.f;
    float g = (r==c) ? dsc : 0.f;
    float ck = 1.f;
    #pragma unroll
    for (int k=1;k<=13;k++){
      ck *= dsc * invk[k];
      float gk = ck * dsc / (float)(k+1);
      float ap = ApL[(k-1)*256 + tid];
      e = fmaf(ck, ap, e);
      g = fmaf(gk, ap, g);
    }
    for (int it=0; it<s; ++it){
      bufE[tid] = e; bufG[tid] = g;
      __syncthreads();
      float en = 0.f, gn = g;
      #pragma unroll
      for (int k=0;k<16;k++){
        float ek = bufE[r*16+k];
        en = fmaf(ek, bufE[k*16+c], en);
        gn = fmaf(ek, bufG[k*16+c], gn);
      }
      e = en; g = gn;
      __syncthreads();
    }
    size_t o = (size_t)i*256 + tid;
    Etab[o] = e;
    Gtab[o] = g;
    bufE[tid] = e;
    __syncthreads();
    float de = 0.f;
    #pragma unroll
    for (int q4=0;q4<4;q4++){           // replicate old fma nesting: k=3..0 per quad
      #pragma unroll
      for (int kk=3;kk>=0;kk--){
        int k = q4*4 + kk;
        de = fmaf(ApL[r*16+k], bufE[k*16+c], de);
      }
    }
    dEtab[o] = de;
    return;
  }
  // ---- cast / split / zero path ----
  const int N1 = 3*II*DD/4;            // 294912 float4 units
  const int N2 = N1 + DD*II/4;         // +98304
  const int N3 = N2 + NS*II;           // +12288 scalar units
  const int N4 = N3 + MT/4;            // +4096 float4 units
  int i = (blockIdx.x - NT)*256 + tid;
  if (i < N1){
    float4 v = *(const float4*)&W_in[(size_t)i*4];
    ushort4 o = make_ushort4(f2bf_bits(v.x), f2bf_bits(v.y), f2bf_bits(v.z), f2bf_bits(v.w));
    *(ushort4*)&Winbf[(size_t)i*4] = o;
  } else if (i < N2){
    int j = i - N1;
    float4 v = *(const float4*)&Wout[(size_t)j*4];
    ushort4 o = make_ushort4(f2bf_bits(v.x), f2bf_bits(v.y), f2bf_bits(v.z), f2bf_bits(v.w));
    *(ushort4*)&Woutbf[(size_t)j*4] = o;
  } else if (i < N3){
    int j = i - N2;
    float f = Bm[j];
    unsigned short hb = f2bf_bits(f);
    Bmhi[j] = __builtin_bit_cast(bf16, hb);
    Bmlo[j] = __float2bfloat16(f - bfbits2f((short)hb));
  } else if (i < N4){
    int j = i - N3;
    float4 z = make_float4(0.f,0.f,0.f,0.f);
    *(float4*)&dacc[(size_t)j*4] = z;
  }
}

// ---------------- LayerNorm: wave per row, float4 ----------------
__global__ __launch_bounds__(256) void ln_kernel(
    const float* __restrict__ x, const float* __restrict__ g,
    const float* __restrict__ b, bf16* __restrict__ h)
{
  int w = threadIdx.x >> 6, l = threadIdx.x & 63;
  int m = blockIdx.x*4 + w;
  const float* xr = x + (size_t)m*DD;
  float4 v0 = *(const float4*)&xr[l*4];
  float4 v1 = *(const float4*)&xr[256 + l*4];
  float s  = v0.x+v0.y+v0.z+v0.w + v1.x+v1.y+v1.z+v1.w;
  float sq = v0.x*v0.x+v0.y*v0.y+v0.z*v0.z+v0.w*v0.w
           + v1.x*v1.x+v1.y*v1.y+v1.z*v1.z+v1.w*v1.w;
  #pragma unroll
  for (int o=1;o<64;o<<=1){ s += __shfl_xor(s,o); sq += __shfl_xor(sq,o); }
  float mu  = s*(1.f/DD);
  float var = sq*(1.f/DD) - mu*mu;
  float rs  = rsqrtf(var + 1e-5f);
  float4 g0 = *(const float4*)&g[l*4];
  float4 b0 = *(const float4*)&b[l*4];
  float4 g1 = *(const float4*)&g[256 + l*4];
  float4 b1 = *(const float4*)&b[256 + l*4];
  ushort4 o0, o1;
  o0.x = f2bf_bits((v0.x-mu)*rs*g0.x + b0.x);
  o0.y = f2bf_bits((v0.y-mu)*rs*g0.y + b0.y);
  o0.z = f2bf_bits((v0.z-mu)*rs*g0.z + b0.z);
  o0.w = f2bf_bits((v0.w-mu)*rs*g0.w + b0.w);
  o1.x = f2bf_bits((v1.x-mu)*rs*g1.x + b1.x);
  o1.y = f2bf_bits((v1.y-mu)*rs*g1.y + b1.y);
  o1.z = f2bf_bits((v1.z-mu)*rs*g1.z + b1.z);
  o1.w = f2bf_bits((v1.w-mu)*rs*g1.w + b1.w);
  *(ushort4*)&h[(size_t)m*DD + l*4]       = o0;
  *(ushort4*)&h[(size_t)m*DD + 256 + l*4] = o1;
}

// ====== GEMM v8 (proven): 128x128 LDS-staged tiles, 2-barrier K-loop ======

// ---------------- GEMM1: proj = h @ W_in^T. grid 2304 = 128 Mtiles x 18 Ntiles ----
__global__ __launch_bounds__(256, 3) void gemm1_mfma(
    const bf16* __restrict__ Ah, const bf16* __restrict__ Bw,
    bf16* __restrict__ databf, bf16* __restrict__ gatebf, float* __restrict__ dacc)
{
  __shared__ alignas(16) bf16 As[128*64];   // 16 KB
  __shared__ alignas(16) bf16 Bs[128*64];   // 16 KB
  const int tid = threadIdx.x, l = tid & 63, w = tid >> 6;
  const int lrow = l & 15, lgrp = l >> 4;
  const int orig = blockIdx.x;
  const int swz = (orig & 7) * (2304/8) + (orig >> 3);   // XCD-chunked (2304%8==0)
  const int bm = (swz / 18) * 128;
  const int bn = swz % 18;
  const int wrow = (w >> 1) * 64, wcol = (w & 1) * 64;

  f32x4 acc[4][4];
  #pragma unroll
  for (int i=0;i<4;i++){
    #pragma unroll
    for (int f=0;f<4;f++){ f32x4 z={0.f,0.f,0.f,0.f}; acc[i][f]=z; }
  }

  for (int t=0; t<8; ++t){                  // K = 512 = 8 x 64
    #pragma unroll
    for (int it=0; it<4; ++it){             // A: 128 rows x 8 segs = 1024
      int d = tid + it*256;
      int r = d >> 3, s = d & 7;
      gload16(Ah + (size_t)(bm + r)*DD + t*64 + ((s ^ (r&7))<<3),
              (char*)As + (size_t)(d - l)*16);
    }
    #pragma unroll
    for (int it=0; it<4; ++it){             // B: 128 cols x 8 segs = 1024
      int d = tid + it*256;
      int r = d >> 3, s = d & 7;
      gload16(Bw + (size_t)(bn*128 + r)*DD + t*64 + ((s ^ (r&7))<<3),
              (char*)Bs + (size_t)(d - l)*16);
    }
    __syncthreads();                        // drains vmcnt -> LDS tiles ready
    #pragma unroll
    for (int kk=0; kk<2; ++kk){
      bf16x8 afr[4], bfr[4];
      #pragma unroll
      for (int i=0;i<4;i++) afr[i] = lds_a_frag<64>(As, wrow + i*16 + lrow, kk*4 + lgrp);
      #pragma unroll
      for (int f=0;f<4;f++) bfr[f] = lds_a_frag<64>(Bs, wcol + f*16 + lrow, kk*4 + lgrp);
      #pragma unroll
      for (int i=0;i<4;i++){
        #pragma unroll
        for (int f=0;f<4;f++)
          acc[i][f] = __builtin_amdgcn_mfma_f32_16x16x32_bf16(afr[i], bfr[f], acc[i][f], 0,0,0);
      }
    }
    __syncthreads();                        // protect LDS before next stage
  }

  // Fused epilogue by N-region (768 = 6 tiles of 128; tiles never straddle)
  const int rowb = bm + wrow + lgrp*4;
  const int cglob = bn*128 + wcol + lrow;
  if (bn < 6){                              // data -> bf16
    #pragma unroll
    for (int i=0;i<4;i++){
      #pragma unroll
      for (int f=0;f<4;f++){
        int col = cglob + f*16;
        #pragma unroll
        for (int j=0;j<4;j++)
          databf[(size_t)(rowb + i*16 + j)*II + col] = __float2bfloat16(acc[i][f][j]);
      }
    }
  } else if (bn < 12){                      // gate -> sigmoid -> bf16
    #pragma unroll
    for (int i=0;i<4;i++){
      #pragma unroll
      for (int f=0;f<4;f++){
        int col = cglob - 768 + f*16;
        #pragma unroll
        for (int j=0;j<4;j++)
          gatebf[(size_t)(rowb + i*16 + j)*II + col] = __float2bfloat16(fsigm(acc[i][f][j]));
      }
    }
  } else {                                  // delta: softplus row-sum -> atomic
    #pragma unroll
    for (int i=0;i<4;i++){
      #pragma unroll
      for (int j=0;j<4;j++){
        float v = fsoftp(acc[i][0][j]) + fsoftp(acc[i][1][j])
                + fsoftp(acc[i][2][j]) + fsoftp(acc[i][3][j]);
        v += __shfl_xor(v,1); v += __shfl_xor(v,2);
        v += __shfl_xor(v,4); v += __shfl_xor(v,8);
        if (lrow == 0) atomicAdd(&dacc[rowb + i*16 + j], v);
      }
    }
  }
}

// ---------------- GEMM2: out = x + selg @ W_out^T. grid 512 = 128 x 4 ----------------
__global__ __launch_bounds__(256, 3) void gemm2_mfma(
    const bf16* __restrict__ Asel, const bf16* __restrict__ Bw,
    const float* __restrict__ x, float* __restrict__ out)
{
  __shared__ alignas(16) bf16 As[128*64];
  __shared__ alignas(16) bf16 Bs[128*64];
  const int tid = threadIdx.x, l = tid & 63, w = tid >> 6;
  const int lrow = l & 15, lgrp = l >> 4;
  const int orig = blockIdx.x;
  const int swz = (orig & 7) * (512/8) + (orig >> 3);    // 512%8==0
  const int bm = (swz >> 2) * 128;
  const int bn = swz & 3;
  const int wrow = (w >> 1) * 64, wcol = (w & 1) * 64;

  f32x4 acc[4][4];
  #pragma unroll
  for (int i=0;i<4;i++){
    #pragma unroll
    for (int f=0;f<4;f++){ f32x4 z={0.f,0.f,0.f,0.f}; acc[i][f]=z; }
  }

  for (int t=0; t<12; ++t){                 // K = 768 = 12 x 64
    #pragma unroll
    for (int it=0; it<4; ++it){
      int d = tid + it*256;
      int r = d >> 3, s = d & 7;
      gload16(Asel + (size_t)(bm + r)*II + t*64 + ((s ^ (r&7))<<3),
              (char*)As + (size_t)(d - l)*16);
    }
    #pragma unroll
    for (int it=0; it<4; ++it){
      int d = tid + it*256;
      int r = d >> 3, s = d & 7;
      gload16(Bw + (size_t)(bn*128 + r)*II + t*64 + ((s ^ (r&7))<<3),
              (char*)Bs + (size_t)(d - l)*16);
    }
    __syncthreads();
    #pragma unroll
    for (int kk=0; kk<2; ++kk){
      bf16x8 afr[4], bfr[4];
      #pragma unroll
      for (int i=0;i<4;i++) afr[i] = lds_a_frag<64>(As, wrow + i*16 + lrow, kk*4 + lgrp);
      #pragma unroll
      for (int f=0;f<4;f++) bfr[f] = lds_a_frag<64>(Bs, wcol + f*16 + lrow, kk*4 + lgrp);
      #pragma unroll
      for (int i=0;i<4;i++){
        #pragma unroll
        for (int f=0;f<4;f++)
          acc[i][f] = __builtin_amdgcn_mfma_f32_16x16x32_bf16(afr[i], bfr[f], acc[i][f], 0,0,0);
      }
    }
    __syncthreads();
  }

  const int rowb = bm + wrow + lgrp*4;
  #pragma unroll
  for (int i=0;i<4;i++){
    #pragma unroll
    for (int f=0;f<4;f++){
      int col = bn*128 + wcol + f*16 + lrow;
      #pragma unroll
      for (int j=0;j<4;j++){
        size_t e = (size_t)(rowb + i*16 + j)*DD + col;
        out[e] = acc[i][f][j] + x[e];
      }
    }
  }
}

// ======== convw via MFMA v3 + XCD-aligned remap ====
__global__ __launch_bounds__(256) void convw_mfma(
    const bf16* __restrict__ data, const float* __restrict__ cw,
    const bf16* __restrict__ Bmhi, const bf16* __restrict__ Bmlo,
    float* __restrict__ w_all)
{
  __shared__ alignas(16) bf16  Ds[1728*8];     // 27.6 KB: [seg 0..95][row 0..17] x 16B
  __shared__ alignas(16) float cwl[II*3];      // 9.2 KB
  __shared__ alignas(16) float red[4][256];    // 4 KB
  const int tid = threadIdx.x, l = tid & 63, wv = tid >> 6;
  const int lrow = l & 15, lgrp = l >> 4;
  const int gblk = (blockIdx.x & 7)*128 + (blockIdx.x >> 3);  // XCD-aligned (1024%8==0)
  const int p0 = gblk * 16;
  const int p  = p0 + lrow;
  const int t  = p & (SS-1);
  const int bstart = p0 & ~(SS-1);
  const float mask1 = (t>=1) ? 1.f : 0.f;
  const float mask0 = (t>=2) ? 1.f : 0.f;

  #pragma unroll
  for (int it=0; it<7; ++it){                  // 96 segs x 18 rows = 1728 units
    int d = tid + it*256;
    if (d < 1728){                             // 1728 = 27 waves -> wave-aligned guard
      int r = d % 18, s2 = d / 18;
      int prow = p0 - 2 + r; if (prow < bstart) prow = bstart;
      gload16(data + (size_t)prow*II + s2*8, (char*)Ds + (size_t)(d - l)*16);
    }
  }
  #pragma unroll
  for (int it=0; it<3; ++it){                  // 2304 floats = 576 units
    int d = tid + it*256;
    if (d < 576)
      gload16f(cw + d*4, (char*)cwl + (size_t)(d - l)*16);
  }
  __syncthreads();

  const int sB = wv*24 + lgrp;                 // lane's base seg (window stride 4)
  const char* DsB = (const char*)Ds + ((size_t)sB*18 + lrow)*16;
  const bf16* bh  = Bmhi + (size_t)lrow*II + sB*8;
  const bf16* bl  = Bmlo + (size_t)lrow*II + sB*8;
  const float* cwp = cwl + sB*24;

  f32x4 acc = {0.f,0.f,0.f,0.f};
  #pragma unroll
  for (int u=0; u<6; ++u){
    bf16x8 v0 = *(const bf16x8*)(DsB + (size_t)u*72*16);        // row p-2
    bf16x8 v1 = *(const bf16x8*)(DsB + (size_t)u*72*16 + 16);   // row p-1
    bf16x8 v2 = *(const bf16x8*)(DsB + (size_t)u*72*16 + 32);   // row p
    bf16x8 ah = *(const bf16x8*)(bh + u*32);
    bf16x8 al = *(const bf16x8*)(bl + u*32);
    float cv[24];
    #pragma unroll
    for (int q=0;q<6;q++){
      float4 cq = *(const float4*)(cwp + u*96 + q*4);
      cv[q*4+0]=cq.x; cv[q*4+1]=cq.y; cv[q*4+2]=cq.z; cv[q*4+3]=cq.w;
    }
    bf16x8 Bh, Bl;
    #pragma unroll
    for (int j=0;j<8;j++){
      float d2 = bfbits2f(v2[j]);
      float d1 = bfbits2f(v1[j]) * mask1;
      float d0 = bfbits2f(v0[j]) * mask0;
      float a = fmaf(d0, cv[3*j], fmaf(d1, cv[3*j+1], d2*cv[3*j+2]));
      float u2 = a * fsigm(a);
      unsigned short hb = f2bf_bits(u2);
      Bh[j] = (short)hb;
      Bl[j] = (short)f2bf_bits(u2 - bfbits2f((short)hb));
    }
    acc = __builtin_amdgcn_mfma_f32_16x16x32_bf16(ah, Bh, acc, 0,0,0);
    acc = __builtin_amdgcn_mfma_f32_16x16x32_bf16(ah, Bl, acc, 0,0,0);
    acc = __builtin_amdgcn_mfma_f32_16x16x32_bf16(al, Bh, acc, 0,0,0);
  }
  *(f32x4*)&red[wv][l*4] = acc;
  __syncthreads();
  if (wv == 0){
    f32x4 s0 = *(const f32x4*)&red[0][l*4];
    f32x4 s1 = *(const f32x4*)&red[1][l*4];
    f32x4 s2 = *(const f32x4*)&red[2][l*4];
    f32x4 s3 = *(const f32x4*)&red[3][l*4];
    f32x4 s = s0 + s1 + s2 + s3;
    *(f32x4*)&w_all[(size_t)p*NS + lgrp*4] = s;
  }
}

// ------- scan pass 1 v3 + XCD-aligned remap (chunk cc -> XCD cc/64 = batch) -------
__global__ __launch_bounds__(256) void scan1_kernel(
    const float* __restrict__ Etab, const float* __restrict__ Gtab,
    const float* __restrict__ dEtab, const float* __restrict__ dacc,
    const float* __restrict__ w_all,
    float* __restrict__ c_all, float* __restrict__ P, float* __restrict__ q)
{
  int cc = (blockIdx.x & 7)*64 + (blockIdx.x >> 3);   // 512%8==0, bijective
  int bb = cc / NCB, ci = cc % NCB;
  size_t base = (size_t)bb*SS + (size_t)ci*CH;
  int tid = threadIdx.x;
  int i = tid>>4, j = tid&15;
  __shared__ float Et[CH][256];   // 32 KB, transposed per t
  __shared__ float cb[CH][16];    // 2 KB
  __shared__ float Pb[2][256];
  __shared__ float qb[2][16];
  Pb[0][tid] = (i==j)?1.f:0.f;
  if (tid<16) qb[0][tid]=0.f;
  const float hh = 3.f/(float)(NT-1);
  // ---- Phase 1: no barriers, all t independent ----
  for (int t=0;t<CH;t++){
    size_t m = base + t;
    float delta = fminf(dacc[m]*(1.f/II) + 1e-4f, 3.0f);
    float tf = delta * (float)(NT-1) * (1.f/3.f);
    int i0 = (int)tf;
    if (i0 > NT-2) i0 = NT-2;
    float fr = tf - (float)i0;
    float fr2 = fr*fr, fr3 = fr2*fr;
    float h00 = 2.f*fr3 - 3.f*fr2 + 1.f;
    float h10 = fr3 - 2.f*fr2 + fr;
    float h01 = -2.f*fr3 + 3.f*fr2;
    float h11 = fr3 - fr2;
    size_t o0 = (size_t)i0*256 + tid;
    float E0 = Etab[o0], E1 = Etab[o0+256];
    float D0 = dEtab[o0], D1 = dEtab[o0+256];
    float G0 = Gtab[o0], G1 = Gtab[o0+256];
    float e = h00*E0 + h01*E1 + hh*(h10*D0 + h11*D1);
    float g = h00*G0 + h01*G1 + hh*(h10*E0 + h11*E1);   // dG/ddelta = E
    Et[t][j*16 + i] = e;                   // transposed store
    float cv = g * w_all[m*NS + j];
    cv += __shfl_xor(cv,1); cv += __shfl_xor(cv,2);
    cv += __shfl_xor(cv,4); cv += __shfl_xor(cv,8);
    if (j==0){ c_all[m*NS + i] = cv; cb[t][i] = cv; }
  }
  __syncthreads();
  // ---- Phase 2: serial recurrence, 1 barrier/step ----
  int cur = 0;
  for (int t=0;t<CH;t++){
    float acc2 = 0.f;
    #pragma unroll
    for (int k=0;k<16;k++) acc2 = fmaf(Et[t][k*16+i], Pb[cur][k*16+j], acc2);
    float qa = 0.f;
    if (j==0){
      #pragma unroll
      for (int k=0;k<16;k++) qa = fmaf(Et[t][k*16+i], qb[cur][k], qa);
      qa += cb[t][i];
    }
    Pb[cur^1][tid] = acc2;
    if (j==0) qb[cur^1][i] = qa;
    __syncthreads();
    cur ^= 1;
  }
  P[(size_t)cc*256 + tid] = Pb[cur][tid];
  if (tid<16) q[(size_t)cc*NS + tid] = qb[cur][tid];
}

// -------- scan pass 2 v3: full-batch LDS staging, barrier-free shuffle chain --------
__global__ __launch_bounds__(64) void scan2_kernel(
    const float* __restrict__ P, const float* __restrict__ q,
    float* __restrict__ entry)
{
  __shared__ alignas(16) float Pall[NCB*256];   // 64 KB
  __shared__ alignas(16) float qall[NCB*16];    // 4 KB
  int b = blockIdx.x;
  int l = threadIdx.x;
  #pragma unroll 4
  for (int it=0; it<64; ++it){                  // 16384 floats = 4096 x 16B units
    int d = l + it*64;
    gload16f(P + (size_t)(b*NCB)*256 + (size_t)d*4, (char*)Pall + (size_t)(d - l)*16);
  }
  #pragma unroll
  for (int it=0; it<4; ++it){                   // 1024 floats = 256 units
    int d = l + it*64;
    gload16f(q + (size_t)(b*NCB)*NS + (size_t)d*4, (char*)qall + (size_t)(d - l)*16);
  }
  __syncthreads();                              // single vmcnt drain
  float e = 0.f;                                // lane l<16 holds e[l]
  for (int ci=0; ci<NCB; ++ci){
    int cc = b*NCB + ci;
    if (l < 16) entry[(size_t)cc*NS + l] = e;   // pre-update state (off chain)
    float a = (l < 16) ? qall[ci*16 + l] : 0.f;
    #pragma unroll
    for (int k=0;k<16;k++){
      float ek = __shfl(e, k);
      a = fmaf(Pall[ci*256 + (l&15)*16 + k], ek, a);
    }
    e = (l < 16) ? a : 0.f;
  }
}

// ------- scan3sel v4 + XCD-aligned remap -------
__global__ __launch_bounds__(256) void scan3sel_kernel(
    const float* __restrict__ Etab, const float* __restrict__ dEtab,
    const float* __restrict__ dacc, const float* __restrict__ c_all,
    const float* __restrict__ entry, const float* __restrict__ Cm,
    const bf16* __restrict__ gate, bf16* __restrict__ selg)
{
  __shared__ alignas(16) float Ads[CH*256];    // 32 KB, swizzled
  __shared__ alignas(16) float cl[CH*16];      // 2 KB
  int cc = (blockIdx.x & 7)*64 + (blockIdx.x >> 3);   // 512%8==0, bijective
  int bb = cc / NCB, ci = cc % NCB;
  size_t base = (size_t)bb*SS + (size_t)ci*CH;
  int tid = threadIdx.x, l = tid & 63, w = tid >> 6;
  int r = l & 15;
  int i = tid >> 4, j = tid & 15;
  if (tid < 128)                               // stage c: 512 floats = 128 units
    gload16f(c_all + base*NS + tid*4, (char*)cl + (size_t)(tid - l)*16);

  // Cm columns for this thread -> registers (fixed cols, loaded once)
  float cmr[3][16];
  #pragma unroll
  for (int p=0;p<3;p++){
    int jcol = w*192 + p*64 + l;
    #pragma unroll
    for (int q4=0;q4<4;q4++){
      float4 cv = *(const float4*)&Cm[jcol*16 + q4*4];
      cmr[p][q4*4+0]=cv.x; cmr[p][q4*4+1]=cv.y;
      cmr[p][q4*4+2]=cv.z; cmr[p][q4*4+3]=cv.w;
    }
  }

  // Recompute E for all t (no barriers; loads pipeline across t)
  const float hh = 3.f/(float)(NT-1);
  const int wslot = (j>>2) ^ ((i>>1)&3);
  const int woff  = i*16 + wslot*4 + (j&3);
  for (int t=0;t<CH;t++){
    size_t m = base + t;
    float delta = fminf(dacc[m]*(1.f/II) + 1e-4f, 3.0f);
    float tf = delta * (float)(NT-1) * (1.f/3.f);
    int i0 = (int)tf;
    if (i0 > NT-2) i0 = NT-2;
    float fr = tf - (float)i0;
    float fr2 = fr*fr, fr3 = fr2*fr;
    float h00 = 2.f*fr3 - 3.f*fr2 + 1.f;
    float h10 = fr3 - 2.f*fr2 + fr;
    float h01 = -2.f*fr3 + 3.f*fr2;
    float h11 = fr3 - fr2;
    size_t o0 = (size_t)i0*256 + tid;
    float E0 = Etab[o0], E1 = Etab[o0+256];
    float D0 = dEtab[o0], D1 = dEtab[o0+256];
    Ads[t*256 + woff] = h00*E0 + h01*E1 + hh*(h10*D0 + h11*D1);
  }
  float g[16];
  #pragma unroll
  for (int k=0;k<16;k++) g[k] = entry[(size_t)cc*NS + k];
  __syncthreads();                             // Ads, cl ready

  const int frm = (r>>1)&3;
  for (int t=0;t<CH;t++){
    size_t m = base + t;
    float s = cl[t*16 + r];
    #pragma unroll
    for (int q4=0;q4<4;q4++){
      float4 ev = *(const float4*)&Ads[(t*64 + r*4 + (q4 ^ frm))*4];
      s = fmaf(ev.x, g[q4*4+0], s);
      s = fmaf(ev.y, g[q4*4+1], s);
      s = fmaf(ev.z, g[q4*4+2], s);
      s = fmaf(ev.w, g[q4*4+3], s);
    }
    #pragma unroll
    for (int k=0;k<16;k++) g[k] = __shfl(s, k);
    #pragma unroll
    for (int p=0;p<3;p++){
      int jcol = w*192 + p*64 + l;
      float y = 0.f;
      #pragma unroll
      for (int k=0;k<16;k++) y = fmaf(cmr[p][k], g[k], y);
      size_t e = m*II + jcol;
      float gv = __bfloat162float(gate[e]);
      selg[e] = __float2bfloat16(gv*y);
    }
  }
}

extern "C" void kernel_launch(void* const* d_in, const int* in_sizes, int n_in,
                              void* d_out, int out_size, void* d_ws, size_t ws_size,
                              hipStream_t stream) {
  (void)in_sizes; (void)n_in; (void)out_size; (void)ws_size;
  const float* x      = (const float*)d_in[0];
  const float* ln_g   = (const float*)d_in[1];
  const float* ln_b   = (const float*)d_in[2];
  const float* W_in   = (const float*)d_in[3];
  const float* conv_w = (const float*)d_in[4];
  const float* A      = (const float*)d_in[5];
  const float* Bm     = (const float*)d_in[6];
  const float* Cm     = (const float*)d_in[7];
  const float* Wout   = (const float*)d_in[8];
  float* out = (float*)d_out;

  char* ws = (char*)d_ws;
  size_t off = 0;
  #define WSALLOC(ty, name, count) \
    ty* name = (ty*)(ws + off); off += (((size_t)(count))*sizeof(ty) + 255) & ~(size_t)255;
  WSALLOC(bf16,  hbf,    (size_t)MT*DD)     // 16.8 MB
  WSALLOC(bf16,  databf, (size_t)MT*II)     // 25.2 MB (reused as selg)
  WSALLOC(bf16,  gatebf, (size_t)MT*II)     // 25.2 MB
  WSALLOC(float, dacc,   MT)
  WSALLOC(float, w_all,  (size_t)MT*NS)
  WSALLOC(float, c_all,  (size_t)MT*NS)
  WSALLOC(float, Pbuf,   (size_t)NCHK*256)
  WSALLOC(float, qbuf,   (size_t)NCHK*NS)
  WSALLOC(float, entry,  (size_t)NCHK*NS)
  WSALLOC(bf16,  Winbf,  (size_t)3*II*DD)   // 2.36 MB
  WSALLOC(bf16,  Woutbf, (size_t)DD*II)     // 0.79 MB
  WSALLOC(bf16,  Bmhi,   (size_t)NS*II)
  WSALLOC(bf16,  Bmlo,   (size_t)NS*II)
  WSALLOC(float, Etab,   (size_t)NT*256)    // 1 MB
  WSALLOC(float, Gtab,   (size_t)NT*256)    // 1 MB
  WSALLOC(float, dEtab,  (size_t)NT*256)    // 1 MB
  #undef WSALLOC

  prep_etab_kernel<<<NT + 1600, 256, 0, stream>>>(
      W_in, Wout, Bm, A, Winbf, Woutbf, Bmhi, Bmlo, dacc, Etab, Gtab, dEtab);
  ln_kernel    <<<MT/4, 256, 0, stream>>>(x, ln_g, ln_b, hbf);
  gemm1_mfma   <<<dim3(2304), 256, 0, stream>>>(hbf, Winbf, databf, gatebf, dacc);
  convw_mfma   <<<MT/16, 256, 0, stream>>>(databf, conv_w, Bmhi, Bmlo, w_all);
  scan1_kernel <<<NCHK, 256, 0, stream>>>(Etab, Gtab, dEtab, dacc, w_all, c_all, Pbuf, qbuf);
  scan2_kernel <<<BB, 64, 0, stream>>>(Pbuf, qbuf, entry);
  scan3sel_kernel<<<NCHK, 256, 0, stream>>>(Etab, dEtab, dacc, c_all, entry, Cm, gatebf, databf);
  gemm2_mfma   <<<dim3(512), 256, 0, stream>>>(databf, Woutbf, x, out);
}

// Round 14
// 186.728 us; speedup vs baseline: 1.0321x; 1.0321x over previous
//
#include <hip/hip_runtime.h>
#include <hip/hip_bf16.h>
#include <math.h>

// Problem constants
#define BB 8
#define SS 2048
#define DD 512
#define II 768
#define MT (BB*SS)        // 16384 positions
#define NS 16             // state dim
#define CH 32             // scan chunk length
#define NCB (SS/CH)       // 64 chunks per batch
#define NCHK (MT/CH)      // 512 chunks total
#define NT 1024           // expm table size

typedef __hip_bfloat16 bf16;
typedef __attribute__((ext_vector_type(8))) short bf16x8;
typedef __attribute__((ext_vector_type(4))) float f32x4;

__device__ __forceinline__ float fsigm(float x){
  return __builtin_amdgcn_rcpf(1.f + __expf(-x));          // v_exp + v_rcp
}
__device__ __forceinline__ float fsoftp(float x){
  return (x > 15.f) ? x : __logf(1.f + __expf(x));         // v_exp + v_log
}
__device__ __forceinline__ unsigned short f2bf_bits(float f){
  __hip_bfloat16 h = __float2bfloat16(f);
  return __builtin_bit_cast(unsigned short, h);
}
__device__ __forceinline__ float bfbits2f(short s){
  union { float f; unsigned u; } v;
  v.u = ((unsigned)(unsigned short)s) << 16;
  return v.f;
}
__device__ __forceinline__ void gload16(const bf16* src, void* dst){
  __builtin_amdgcn_global_load_lds((const __attribute__((address_space(1))) void*)src,
                                   (__attribute__((address_space(3))) void*)dst, 16, 0, 0);
}
__device__ __forceinline__ void gload16f(const float* src, void* dst){
  __builtin_amdgcn_global_load_lds((const __attribute__((address_space(1))) void*)src,
                                   (__attribute__((address_space(3))) void*)dst, 16, 0, 0);
}
template<int KDIM>
__device__ __forceinline__ bf16x8 lds_a_frag(const bf16* As, int row, int kseg){
  return *(const bf16x8*)((const char*)As + (size_t)row*(KDIM*2)
                          + (size_t)((kseg ^ (row & 7)) << 4));
}

// ------- prep: W_in/W_out cast + Bm hi/lo split + dacc zero + (block 1600) A-powers
__global__ __launch_bounds__(256) void prep_kernel(
    const float* __restrict__ W_in, const float* __restrict__ Wout,
    const float* __restrict__ Bm, const float* __restrict__ A,
    bf16* __restrict__ Winbf, bf16* __restrict__ Woutbf,
    bf16* __restrict__ Bmhi, bf16* __restrict__ Bmlo,
    float* __restrict__ dacc, float* __restrict__ Apow)
{
  __shared__ double Am[256], T0[256], T1[256];
  __shared__ double colsum[16];
  if (blockIdx.x == 1600){                   // ---- A powers (f64, once) ----
    int tid = threadIdx.x, r = tid>>4, c = tid&15;
    double a = (double)A[tid];
    Am[tid] = a; T0[tid] = a;
    Apow[tid] = A[tid];
    __syncthreads();
    double *Tc = T0, *Tn = T1;
    for (int k=2;k<=13;k++){
      double s = 0.0;
      #pragma unroll
      for (int j=0;j<16;j++) s += Tc[r*16+j]*Am[j*16+c];
      Tn[tid] = s;
      Apow[(k-1)*256 + tid] = (float)s;
      __syncthreads();
      double* tmp = Tc; Tc = Tn; Tn = tmp;
    }
    if (tid < 16){
      double s = 0.0;
      #pragma unroll
      for (int j=0;j<16;j++) s += fabs(Am[j*16+tid]);
      colsum[tid] = s;
    }
    __syncthreads();
    if (tid == 0){
      double mx = 0.0;
      #pragma unroll
      for (int j=0;j<16;j++) mx = fmax(mx, colsum[j]);
      Apow[13*256] = (float)mx;
    }
    return;
  }
  const int N1 = 3*II*DD/4;            // 294912 float4 units
  const int N2 = N1 + DD*II/4;         // +98304
  const int N3 = N2 + NS*II;           // +12288 scalar units
  const int N4 = N3 + MT/4;            // +4096 float4 units
  int i = blockIdx.x*256 + threadIdx.x;
  if (i < N1){
    float4 v = *(const float4*)&W_in[(size_t)i*4];
    ushort4 o = make_ushort4(f2bf_bits(v.x), f2bf_bits(v.y), f2bf_bits(v.z), f2bf_bits(v.w));
    *(ushort4*)&Winbf[(size_t)i*4] = o;
  } else if (i < N2){
    int j = i - N1;
    float4 v = *(const float4*)&Wout[(size_t)j*4];
    ushort4 o = make_ushort4(f2bf_bits(v.x), f2bf_bits(v.y), f2bf_bits(v.z), f2bf_bits(v.w));
    *(ushort4*)&Woutbf[(size_t)j*4] = o;
  } else if (i < N3){
    int j = i - N2;
    float f = Bm[j];
    unsigned short hb = f2bf_bits(f);
    Bmhi[j] = __builtin_bit_cast(bf16, hb);
    Bmlo[j] = __float2bfloat16(f - bfbits2f((short)hb));
  } else if (i < N4){
    int j = i - N3;
    float4 z = make_float4(0.f,0.f,0.f,0.f);
    *(float4*)&dacc[(size_t)j*4] = z;
  }
}

// ---------------- expm table: E(d_i), G(d_i)=Ainv(E-I), dE(d_i)=A*E ----------------
__global__ __launch_bounds__(64) void etab_kernel(
    const float* __restrict__ Apow, float* __restrict__ Etab,
    float* __restrict__ Gtab, float* __restrict__ dEtab)
{
  int i = blockIdx.x;
  int l = threadIdx.x;
  int r = l&15, gq = l>>4, c0 = gq*4;
  __shared__ alignas(16) float bufE[256];
  __shared__ alignas(16) float bufG[256];
  float delta = (3.0f*i)/(float)(NT-1);
  float anorm = Apow[13*256];
  float mx = delta*anorm;
  int s = 0;
  if (mx > 2.f){
    s = (int)ceilf(log2f(mx)) - 1;
    if (s < 0) s = 0;
    if (s > 12) s = 12;
  }
  float dsc = ldexpf(delta, -s);
  const float invk[14]  = {0.f, 1.f, 0.5f, 1.f/3.f, 0.25f, 0.2f, 1.f/6.f, 1.f/7.f,
                           0.125f, 1.f/9.f, 0.1f, 1.f/11.f, 1.f/12.f, 1.f/13.f};
  float4 e = make_float4(0.f,0.f,0.f,0.f), g = e;
  if (r==c0  ){ e.x = 1.f; g.x = dsc; }
  if (r==c0+1){ e.y = 1.f; g.y = dsc; }
  if (r==c0+2){ e.z = 1.f; g.z = dsc; }
  if (r==c0+3){ e.w = 1.f; g.w = dsc; }
  float ck = 1.f;
  #pragma unroll
  for (int k=1;k<=13;k++){
    ck *= dsc * invk[k];
    float gk = ck * dsc / (float)(k+1);
    float4 ap = *(const float4*)&Apow[(k-1)*256 + r*16 + c0];
    e.x = fmaf(ck, ap.x, e.x); e.y = fmaf(ck, ap.y, e.y);
    e.z = fmaf(ck, ap.z, e.z); e.w = fmaf(ck, ap.w, e.w);
    g.x = fmaf(gk, ap.x, g.x); g.y = fmaf(gk, ap.y, g.y);
    g.z = fmaf(gk, ap.z, g.z); g.w = fmaf(gk, ap.w, g.w);
  }
  for (int it=0; it<s; ++it){
    *(float4*)&bufE[r*16+c0] = e;
    *(float4*)&bufG[r*16+c0] = g;
    __syncthreads();
    float erow[16];
    #pragma unroll
    for (int q4=0;q4<4;q4++){
      float4 tv = *(const float4*)&bufE[r*16+q4*4];
      erow[q4*4+0]=tv.x; erow[q4*4+1]=tv.y; erow[q4*4+2]=tv.z; erow[q4*4+3]=tv.w;
    }
    float4 en = make_float4(0.f,0.f,0.f,0.f);
    float4 gn = g;
    #pragma unroll
    for (int kk=0;kk<16;kk++){
      float4 ev = *(const float4*)&bufE[kk*16+c0];
      float4 gv = *(const float4*)&bufG[kk*16+c0];
      float ek = erow[kk];
      en.x=fmaf(ek,ev.x,en.x); en.y=fmaf(ek,ev.y,en.y);
      en.z=fmaf(ek,ev.z,en.z); en.w=fmaf(ek,ev.w,en.w);
      gn.x=fmaf(ek,gv.x,gn.x); gn.y=fmaf(ek,gv.y,gn.y);
      gn.z=fmaf(ek,gv.z,gn.z); gn.w=fmaf(ek,gv.w,gn.w);
    }
    e = en; g = gn;
    __syncthreads();
  }
  size_t o = (size_t)i*256 + r*16 + c0;
  *(float4*)&Etab[o] = e;
  *(float4*)&Gtab[o] = g;
  *(float4*)&bufE[r*16+c0] = e;
  __syncthreads();
  float4 de = make_float4(0.f,0.f,0.f,0.f);
  #pragma unroll
  for (int q4=0;q4<4;q4++){
    float4 ar = *(const float4*)&Apow[r*16 + q4*4];
    float4 e0 = *(const float4*)&bufE[(q4*4+0)*16 + c0];
    float4 e1 = *(const float4*)&bufE[(q4*4+1)*16 + c0];
    float4 e2 = *(const float4*)&bufE[(q4*4+2)*16 + c0];
    float4 e3 = *(const float4*)&bufE[(q4*4+3)*16 + c0];
    de.x = fmaf(ar.x,e0.x,fmaf(ar.y,e1.x,fmaf(ar.z,e2.x,fmaf(ar.w,e3.x,de.x))));
    de.y = fmaf(ar.x,e0.y,fmaf(ar.y,e1.y,fmaf(ar.z,e2.y,fmaf(ar.w,e3.y,de.y))));
    de.z = fmaf(ar.x,e0.z,fmaf(ar.y,e1.z,fmaf(ar.z,e2.z,fmaf(ar.w,e3.z,de.z))));
    de.w = fmaf(ar.x,e0.w,fmaf(ar.y,e1.w,fmaf(ar.z,e2.w,fmaf(ar.w,e3.w,de.w))));
  }
  *(float4*)&dEtab[o] = de;
}

// ---------------- LayerNorm: wave per row, float4 ----------------
__global__ __launch_bounds__(256) void ln_kernel(
    const float* __restrict__ x, const float* __restrict__ g,
    const float* __restrict__ b, bf16* __restrict__ h)
{
  int w = threadIdx.x >> 6, l = threadIdx.x & 63;
  int m = blockIdx.x*4 + w;
  const float* xr = x + (size_t)m*DD;
  float4 v0 = *(const float4*)&xr[l*4];
  float4 v1 = *(const float4*)&xr[256 + l*4];
  float s  = v0.x+v0.y+v0.z+v0.w + v1.x+v1.y+v1.z+v1.w;
  float sq = v0.x*v0.x+v0.y*v0.y+v0.z*v0.z+v0.w*v0.w
           + v1.x*v1.x+v1.y*v1.y+v1.z*v1.z+v1.w*v1.w;
  #pragma unroll
  for (int o=1;o<64;o<<=1){ s += __shfl_xor(s,o); sq += __shfl_xor(sq,o); }
  float mu  = s*(1.f/DD);
  float var = sq*(1.f/DD) - mu*mu;
  float rs  = rsqrtf(var + 1e-5f);
  float4 g0 = *(const float4*)&g[l*4];
  float4 b0 = *(const float4*)&b[l*4];
  float4 g1 = *(const float4*)&g[256 + l*4];
  float4 b1 = *(const float4*)&b[256 + l*4];
  ushort4 o0, o1;
  o0.x = f2bf_bits((v0.x-mu)*rs*g0.x + b0.x);
  o0.y = f2bf_bits((v0.y-mu)*rs*g0.y + b0.y);
  o0.z = f2bf_bits((v0.z-mu)*rs*g0.z + b0.z);
  o0.w = f2bf_bits((v0.w-mu)*rs*g0.w + b0.w);
  o1.x = f2bf_bits((v1.x-mu)*rs*g1.x + b1.x);
  o1.y = f2bf_bits((v1.y-mu)*rs*g1.y + b1.y);
  o1.z = f2bf_bits((v1.z-mu)*rs*g1.z + b1.z);
  o1.w = f2bf_bits((v1.w-mu)*rs*g1.w + b1.w);
  *(ushort4*)&h[(size_t)m*DD + l*4]       = o0;
  *(ushort4*)&h[(size_t)m*DD + 256 + l*4] = o1;
}

// ====== GEMM v8 (proven): 128x128 LDS-staged tiles, 2-barrier K-loop ======

// ---------------- GEMM1: proj = h @ W_in^T. grid 2304 = 128 Mtiles x 18 Ntiles ----
__global__ __launch_bounds__(256, 3) void gemm1_mfma(
    const bf16* __restrict__ Ah, const bf16* __restrict__ Bw,
    bf16* __restrict__ databf, bf16* __restrict__ gatebf, float* __restrict__ dacc)
{
  __shared__ alignas(16) bf16 As[128*64];   // 16 KB
  __shared__ alignas(16) bf16 Bs[128*64];   // 16 KB
  const int tid = threadIdx.x, l = tid & 63, w = tid >> 6;
  const int lrow = l & 15, lgrp = l >> 4;
  const int orig = blockIdx.x;
  const int swz = (orig & 7) * (2304/8) + (orig >> 3);   // XCD-chunked (2304%8==0)
  const int bm = (swz / 18) * 128;
  const int bn = swz % 18;
  const int wrow = (w >> 1) * 64, wcol = (w & 1) * 64;

  f32x4 acc[4][4];
  #pragma unroll
  for (int i=0;i<4;i++){
    #pragma unroll
    for (int f=0;f<4;f++){ f32x4 z={0.f,0.f,0.f,0.f}; acc[i][f]=z; }
  }

  for (int t=0; t<8; ++t){                  // K = 512 = 8 x 64
    #pragma unroll
    for (int it=0; it<4; ++it){             // A: 128 rows x 8 segs = 1024
      int d = tid + it*256;
      int r = d >> 3, s = d & 7;
      gload16(Ah + (size_t)(bm + r)*DD + t*64 + ((s ^ (r&7))<<3),
              (char*)As + (size_t)(d - l)*16);
    }
    #pragma unroll
    for (int it=0; it<4; ++it){             // B: 128 cols x 8 segs = 1024
      int d = tid + it*256;
      int r = d >> 3, s = d & 7;
      gload16(Bw + (size_t)(bn*128 + r)*DD + t*64 + ((s ^ (r&7))<<3),
              (char*)Bs + (size_t)(d - l)*16);
    }
    __syncthreads();                        // drains vmcnt -> LDS tiles ready
    #pragma unroll
    for (int kk=0; kk<2; ++kk){
      bf16x8 afr[4], bfr[4];
      #pragma unroll
      for (int i=0;i<4;i++) afr[i] = lds_a_frag<64>(As, wrow + i*16 + lrow, kk*4 + lgrp);
      #pragma unroll
      for (int f=0;f<4;f++) bfr[f] = lds_a_frag<64>(Bs, wcol + f*16 + lrow, kk*4 + lgrp);
      #pragma unroll
      for (int i=0;i<4;i++){
        #pragma unroll
        for (int f=0;f<4;f++)
          acc[i][f] = __builtin_amdgcn_mfma_f32_16x16x32_bf16(afr[i], bfr[f], acc[i][f], 0,0,0);
      }
    }
    __syncthreads();                        // protect LDS before next stage
  }

  // Fused epilogue by N-region (768 = 6 tiles of 128; tiles never straddle)
  const int rowb = bm + wrow + lgrp*4;
  const int cglob = bn*128 + wcol + lrow;
  if (bn < 6){                              // data -> bf16
    #pragma unroll
    for (int i=0;i<4;i++){
      #pragma unroll
      for (int f=0;f<4;f++){
        int col = cglob + f*16;
        #pragma unroll
        for (int j=0;j<4;j++)
          databf[(size_t)(rowb + i*16 + j)*II + col] = __float2bfloat16(acc[i][f][j]);
      }
    }
  } else if (bn < 12){                      // gate -> sigmoid -> bf16
    #pragma unroll
    for (int i=0;i<4;i++){
      #pragma unroll
      for (int f=0;f<4;f++){
        int col = cglob - 768 + f*16;
        #pragma unroll
        for (int j=0;j<4;j++)
          gatebf[(size_t)(rowb + i*16 + j)*II + col] = __float2bfloat16(fsigm(acc[i][f][j]));
      }
    }
  } else {                                  // delta: softplus row-sum -> atomic
    #pragma unroll
    for (int i=0;i<4;i++){
      #pragma unroll
      for (int j=0;j<4;j++){
        float v = fsoftp(acc[i][0][j]) + fsoftp(acc[i][1][j])
                + fsoftp(acc[i][2][j]) + fsoftp(acc[i][3][j]);
        v += __shfl_xor(v,1); v += __shfl_xor(v,2);
        v += __shfl_xor(v,4); v += __shfl_xor(v,8);
        if (lrow == 0) atomicAdd(&dacc[rowb + i*16 + j], v);
      }
    }
  }
}

// ---------------- GEMM2: out = x + selg @ W_out^T. grid 512 = 128 x 4 ----------------
__global__ __launch_bounds__(256, 3) void gemm2_mfma(
    const bf16* __restrict__ Asel, const bf16* __restrict__ Bw,
    const float* __restrict__ x, float* __restrict__ out)
{
  __shared__ alignas(16) bf16 As[128*64];
  __shared__ alignas(16) bf16 Bs[128*64];
  const int tid = threadIdx.x, l = tid & 63, w = tid >> 6;
  const int lrow = l & 15, lgrp = l >> 4;
  const int orig = blockIdx.x;
  const int swz = (orig & 7) * (512/8) + (orig >> 3);    // 512%8==0
  const int bm = (swz >> 2) * 128;
  const int bn = swz & 3;
  const int wrow = (w >> 1) * 64, wcol = (w & 1) * 64;

  f32x4 acc[4][4];
  #pragma unroll
  for (int i=0;i<4;i++){
    #pragma unroll
    for (int f=0;f<4;f++){ f32x4 z={0.f,0.f,0.f,0.f}; acc[i][f]=z; }
  }

  for (int t=0; t<12; ++t){                 // K = 768 = 12 x 64
    #pragma unroll
    for (int it=0; it<4; ++it){
      int d = tid + it*256;
      int r = d >> 3, s = d & 7;
      gload16(Asel + (size_t)(bm + r)*II + t*64 + ((s ^ (r&7))<<3),
              (char*)As + (size_t)(d - l)*16);
    }
    #pragma unroll
    for (int it=0; it<4; ++it){
      int d = tid + it*256;
      int r = d >> 3, s = d & 7;
      gload16(Bw + (size_t)(bn*128 + r)*II + t*64 + ((s ^ (r&7))<<3),
              (char*)Bs + (size_t)(d - l)*16);
    }
    __syncthreads();
    #pragma unroll
    for (int kk=0; kk<2; ++kk){
      bf16x8 afr[4], bfr[4];
      #pragma unroll
      for (int i=0;i<4;i++) afr[i] = lds_a_frag<64>(As, wrow + i*16 + lrow, kk*4 + lgrp);
      #pragma unroll
      for (int f=0;f<4;f++) bfr[f] = lds_a_frag<64>(Bs, wcol + f*16 + lrow, kk*4 + lgrp);
      #pragma unroll
      for (int i=0;i<4;i++){
        #pragma unroll
        for (int f=0;f<4;f++)
          acc[i][f] = __builtin_amdgcn_mfma_f32_16x16x32_bf16(afr[i], bfr[f], acc[i][f], 0,0,0);
      }
    }
    __syncthreads();
  }

  const int rowb = bm + wrow + lgrp*4;
  #pragma unroll
  for (int i=0;i<4;i++){
    #pragma unroll
    for (int f=0;f<4;f++){
      int col = bn*128 + wcol + f*16 + lrow;
      #pragma unroll
      for (int j=0;j<4;j++){
        size_t e = (size_t)(rowb + i*16 + j)*DD + col;
        out[e] = acc[i][f][j] + x[e];
      }
    }
  }
}

// ======== convw via MFMA v3 + XCD-aligned remap ====
__global__ __launch_bounds__(256) void convw_mfma(
    const bf16* __restrict__ data, const float* __restrict__ cw,
    const bf16* __restrict__ Bmhi, const bf16* __restrict__ Bmlo,
    float* __restrict__ w_all)
{
  __shared__ alignas(16) bf16  Ds[1728*8];     // 27.6 KB: [seg 0..95][row 0..17] x 16B
  __shared__ alignas(16) float cwl[II*3];      // 9.2 KB
  __shared__ alignas(16) float red[4][256];    // 4 KB
  const int tid = threadIdx.x, l = tid & 63, wv = tid >> 6;
  const int lrow = l & 15, lgrp = l >> 4;
  const int gblk = (blockIdx.x & 7)*128 + (blockIdx.x >> 3);  // XCD-aligned (1024%8==0)
  const int p0 = gblk * 16;
  const int p  = p0 + lrow;
  const int t  = p & (SS-1);
  const int bstart = p0 & ~(SS-1);
  const float mask1 = (t>=1) ? 1.f : 0.f;
  const float mask0 = (t>=2) ? 1.f : 0.f;

  #pragma unroll
  for (int it=0; it<7; ++it){                  // 96 segs x 18 rows = 1728 units
    int d = tid + it*256;
    if (d < 1728){                             // 1728 = 27 waves -> wave-aligned guard
      int r = d % 18, s2 = d / 18;
      int prow = p0 - 2 + r; if (prow < bstart) prow = bstart;
      gload16(data + (size_t)prow*II + s2*8, (char*)Ds + (size_t)(d - l)*16);
    }
  }
  #pragma unroll
  for (int it=0; it<3; ++it){                  // 2304 floats = 576 units
    int d = tid + it*256;
    if (d < 576)
      gload16f(cw + d*4, (char*)cwl + (size_t)(d - l)*16);
  }
  __syncthreads();

  const int sB = wv*24 + lgrp;                 // lane's base seg (window stride 4)
  const char* DsB = (const char*)Ds + ((size_t)sB*18 + lrow)*16;
  const bf16* bh  = Bmhi + (size_t)lrow*II + sB*8;
  const bf16* bl  = Bmlo + (size_t)lrow*II + sB*8;
  const float* cwp = cwl + sB*24;

  f32x4 acc = {0.f,0.f,0.f,0.f};
  #pragma unroll
  for (int u=0; u<6; ++u){
    bf16x8 v0 = *(const bf16x8*)(DsB + (size_t)u*72*16);        // row p-2
    bf16x8 v1 = *(const bf16x8*)(DsB + (size_t)u*72*16 + 16);   // row p-1
    bf16x8 v2 = *(const bf16x8*)(DsB + (size_t)u*72*16 + 32);   // row p
    bf16x8 ah = *(const bf16x8*)(bh + u*32);
    bf16x8 al = *(const bf16x8*)(bl + u*32);
    float cv[24];
    #pragma unroll
    for (int q=0;q<6;q++){
      float4 cq = *(const float4*)(cwp + u*96 + q*4);
      cv[q*4+0]=cq.x; cv[q*4+1]=cq.y; cv[q*4+2]=cq.z; cv[q*4+3]=cq.w;
    }
    bf16x8 Bh, Bl;
    #pragma unroll
    for (int j=0;j<8;j++){
      float d2 = bfbits2f(v2[j]);
      float d1 = bfbits2f(v1[j]) * mask1;
      float d0 = bfbits2f(v0[j]) * mask0;
      float a = fmaf(d0, cv[3*j], fmaf(d1, cv[3*j+1], d2*cv[3*j+2]));
      float u2 = a * fsigm(a);
      unsigned short hb = f2bf_bits(u2);
      Bh[j] = (short)hb;
      Bl[j] = (short)f2bf_bits(u2 - bfbits2f((short)hb));
    }
    acc = __builtin_amdgcn_mfma_f32_16x16x32_bf16(ah, Bh, acc, 0,0,0);
    acc = __builtin_amdgcn_mfma_f32_16x16x32_bf16(ah, Bl, acc, 0,0,0);
    acc = __builtin_amdgcn_mfma_f32_16x16x32_bf16(al, Bh, acc, 0,0,0);
  }
  *(f32x4*)&red[wv][l*4] = acc;
  __syncthreads();
  if (wv == 0){
    f32x4 s0 = *(const f32x4*)&red[0][l*4];
    f32x4 s1 = *(const f32x4*)&red[1][l*4];
    f32x4 s2 = *(const f32x4*)&red[2][l*4];
    f32x4 s3 = *(const f32x4*)&red[3][l*4];
    f32x4 s = s0 + s1 + s2 + s3;
    *(f32x4*)&w_all[(size_t)p*NS + lgrp*4] = s;
  }
}

// ------- scan pass 1 v3 + XCD-aligned remap (chunk cc -> XCD cc/64 = batch) -------
__global__ __launch_bounds__(256) void scan1_kernel(
    const float* __restrict__ Etab, const float* __restrict__ Gtab,
    const float* __restrict__ dEtab, const float* __restrict__ dacc,
    const float* __restrict__ w_all,
    float* __restrict__ c_all, float* __restrict__ P, float* __restrict__ q)
{
  int cc = (blockIdx.x & 7)*64 + (blockIdx.x >> 3);   // 512%8==0, bijective
  int bb = cc / NCB, ci = cc % NCB;
  size_t base = (size_t)bb*SS + (size_t)ci*CH;
  int tid = threadIdx.x;
  int i = tid>>4, j = tid&15;
  __shared__ float Et[CH][256];   // 32 KB, transposed per t
  __shared__ float cb[CH][16];    // 2 KB
  __shared__ float Pb[2][256];
  __shared__ float qb[2][16];
  Pb[0][tid] = (i==j)?1.f:0.f;
  if (tid<16) qb[0][tid]=0.f;
  const float hh = 3.f/(float)(NT-1);
  // ---- Phase 1: no barriers, all t independent ----
  for (int t=0;t<CH;t++){
    size_t m = base + t;
    float delta = fminf(dacc[m]*(1.f/II) + 1e-4f, 3.0f);
    float tf = delta * (float)(NT-1) * (1.f/3.f);
    int i0 = (int)tf;
    if (i0 > NT-2) i0 = NT-2;
    float fr = tf - (float)i0;
    float fr2 = fr*fr, fr3 = fr2*fr;
    float h00 = 2.f*fr3 - 3.f*fr2 + 1.f;
    float h10 = fr3 - 2.f*fr2 + fr;
    float h01 = -2.f*fr3 + 3.f*fr2;
    float h11 = fr3 - fr2;
    size_t o0 = (size_t)i0*256 + tid;
    float E0 = Etab[o0], E1 = Etab[o0+256];
    float D0 = dEtab[o0], D1 = dEtab[o0+256];
    float G0 = Gtab[o0], G1 = Gtab[o0+256];
    float e = h00*E0 + h01*E1 + hh*(h10*D0 + h11*D1);
    float g = h00*G0 + h01*G1 + hh*(h10*E0 + h11*E1);   // dG/ddelta = E
    Et[t][j*16 + i] = e;                   // transposed store
    float cv = g * w_all[m*NS + j];
    cv += __shfl_xor(cv,1); cv += __shfl_xor(cv,2);
    cv += __shfl_xor(cv,4); cv += __shfl_xor(cv,8);
    if (j==0){ c_all[m*NS + i] = cv; cb[t][i] = cv; }
  }
  __syncthreads();
  // ---- Phase 2: serial recurrence, 1 barrier/step ----
  int cur = 0;
  for (int t=0;t<CH;t++){
    float acc2 = 0.f;
    #pragma unroll
    for (int k=0;k<16;k++) acc2 = fmaf(Et[t][k*16+i], Pb[cur][k*16+j], acc2);
    float qa = 0.f;
    if (j==0){
      #pragma unroll
      for (int k=0;k<16;k++) qa = fmaf(Et[t][k*16+i], qb[cur][k], qa);
      qa += cb[t][i];
    }
    Pb[cur^1][tid] = acc2;
    if (j==0) qb[cur^1][i] = qa;
    __syncthreads();
    cur ^= 1;
  }
  P[(size_t)cc*256 + tid] = Pb[cur][tid];
  if (tid<16) q[(size_t)cc*NS + tid] = qb[cur][tid];
}

// -------- scan pass 2 v3: full-batch LDS staging, barrier-free shuffle chain --------
__global__ __launch_bounds__(64) void scan2_kernel(
    const float* __restrict__ P, const float* __restrict__ q,
    float* __restrict__ entry)
{
  __shared__ alignas(16) float Pall[NCB*256];   // 64 KB
  __shared__ alignas(16) float qall[NCB*16];    // 4 KB
  int b = blockIdx.x;
  int l = threadIdx.x;
  #pragma unroll 4
  for (int it=0; it<64; ++it){                  // 16384 floats = 4096 x 16B units
    int d = l + it*64;
    gload16f(P + (size_t)(b*NCB)*256 + (size_t)d*4, (char*)Pall + (size_t)(d - l)*16);
  }
  #pragma unroll
  for (int it=0; it<4; ++it){                   // 1024 floats = 256 units
    int d = l + it*64;
    gload16f(q + (size_t)(b*NCB)*NS + (size_t)d*4, (char*)qall + (size_t)(d - l)*16);
  }
  __syncthreads();                              // single vmcnt drain
  float e = 0.f;                                // lane l<16 holds e[l]
  for (int ci=0; ci<NCB; ++ci){
    int cc = b*NCB + ci;
    if (l < 16) entry[(size_t)cc*NS + l] = e;   // pre-update state (off chain)
    float a = (l < 16) ? qall[ci*16 + l] : 0.f;
    #pragma unroll
    for (int k=0;k<16;k++){
      float ek = __shfl(e, k);
      a = fmaf(Pall[ci*256 + (l&15)*16 + k], ek, a);
    }
    e = (l < 16) ? a : 0.f;
  }
}

// ------- scan3sel v4 + XCD-aligned remap -------
__global__ __launch_bounds__(256) void scan3sel_kernel(
    const float* __restrict__ Etab, const float* __restrict__ dEtab,
    const float* __restrict__ dacc, const float* __restrict__ c_all,
    const float* __restrict__ entry, const float* __restrict__ Cm,
    const bf16* __restrict__ gate, bf16* __restrict__ selg)
{
  __shared__ alignas(16) float Ads[CH*256];    // 32 KB, swizzled
  __shared__ alignas(16) float cl[CH*16];      // 2 KB
  int cc = (blockIdx.x & 7)*64 + (blockIdx.x >> 3);   // 512%8==0, bijective
  int bb = cc / NCB, ci = cc % NCB;
  size_t base = (size_t)bb*SS + (size_t)ci*CH;
  int tid = threadIdx.x, l = tid & 63, w = tid >> 6;
  int r = l & 15;
  int i = tid >> 4, j = tid & 15;
  if (tid < 128)                               // stage c: 512 floats = 128 units
    gload16f(c_all + base*NS + tid*4, (char*)cl + (size_t)(tid - l)*16);

  // Cm columns for this thread -> registers (fixed cols, loaded once)
  float cmr[3][16];
  #pragma unroll
  for (int p=0;p<3;p++){
    int jcol = w*192 + p*64 + l;
    #pragma unroll
    for (int q4=0;q4<4;q4++){
      float4 cv = *(const float4*)&Cm[jcol*16 + q4*4];
      cmr[p][q4*4+0]=cv.x; cmr[p][q4*4+1]=cv.y;
      cmr[p][q4*4+2]=cv.z; cmr[p][q4*4+3]=cv.w;
    }
  }

  // Recompute E for all t (no barriers; loads pipeline across t)
  const float hh = 3.f/(float)(NT-1);
  const int wslot = (j>>2) ^ ((i>>1)&3);
  const int woff  = i*16 + wslot*4 + (j&3);
  for (int t=0;t<CH;t++){
    size_t m = base + t;
    float delta = fminf(dacc[m]*(1.f/II) + 1e-4f, 3.0f);
    float tf = delta * (float)(NT-1) * (1.f/3.f);
    int i0 = (int)tf;
    if (i0 > NT-2) i0 = NT-2;
    float fr = tf - (float)i0;
    float fr2 = fr*fr, fr3 = fr2*fr;
    float h00 = 2.f*fr3 - 3.f*fr2 + 1.f;
    float h10 = fr3 - 2.f*fr2 + fr;
    float h01 = -2.f*fr3 + 3.f*fr2;
    float h11 = fr3 - fr2;
    size_t o0 = (size_t)i0*256 + tid;
    float E0 = Etab[o0], E1 = Etab[o0+256];
    float D0 = dEtab[o0], D1 = dEtab[o0+256];
    Ads[t*256 + woff] = h00*E0 + h01*E1 + hh*(h10*D0 + h11*D1);
  }
  float g[16];
  #pragma unroll
  for (int k=0;k<16;k++) g[k] = entry[(size_t)cc*NS + k];
  __syncthreads();                             // Ads, cl ready

  const int frm = (r>>1)&3;
  for (int t=0;t<CH;t++){
    size_t m = base + t;
    float s = cl[t*16 + r];
    #pragma unroll
    for (int q4=0;q4<4;q4++){
      float4 ev = *(const float4*)&Ads[(t*64 + r*4 + (q4 ^ frm))*4];
      s = fmaf(ev.x, g[q4*4+0], s);
      s = fmaf(ev.y, g[q4*4+1], s);
      s = fmaf(ev.z, g[q4*4+2], s);
      s = fmaf(ev.w, g[q4*4+3], s);
    }
    #pragma unroll
    for (int k=0;k<16;k++) g[k] = __shfl(s, k);
    #pragma unroll
    for (int p=0;p<3;p++){
      int jcol = w*192 + p*64 + l;
      float y = 0.f;
      #pragma unroll
      for (int k=0;k<16;k++) y = fmaf(cmr[p][k], g[k], y);
      size_t e = m*II + jcol;
      float gv = __bfloat162float(gate[e]);
      selg[e] = __float2bfloat16(gv*y);
    }
  }
}

extern "C" void kernel_launch(void* const* d_in, const int* in_sizes, int n_in,
                              void* d_out, int out_size, void* d_ws, size_t ws_size,
                              hipStream_t stream) {
  (void)in_sizes; (void)n_in; (void)out_size; (void)ws_size;
  const float* x      = (const float*)d_in[0];
  const float* ln_g   = (const float*)d_in[1];
  const float* ln_b   = (const float*)d_in[2];
  const float* W_in   = (const float*)d_in[3];
  const float* conv_w = (const float*)d_in[4];
  const float* A      = (const float*)d_in[5];
  const float* Bm     = (const float*)d_in[6];
  const float* Cm     = (const float*)d_in[7];
  const float* Wout   = (const float*)d_in[8];
  float* out = (float*)d_out;

  char* ws = (char*)d_ws;
  size_t off = 0;
  #define WSALLOC(ty, name, count) \
    ty* name = (ty*)(ws + off); off += (((size_t)(count))*sizeof(ty) + 255) & ~(size_t)255;
  WSALLOC(bf16,  hbf,    (size_t)MT*DD)     // 16.8 MB
  WSALLOC(bf16,  databf, (size_t)MT*II)     // 25.2 MB (reused as selg)
  WSALLOC(bf16,  gatebf, (size_t)MT*II)     // 25.2 MB
  WSALLOC(float, dacc,   MT)
  WSALLOC(float, w_all,  (size_t)MT*NS)
  WSALLOC(float, c_all,  (size_t)MT*NS)
  WSALLOC(float, Pbuf,   (size_t)NCHK*256)
  WSALLOC(float, qbuf,   (size_t)NCHK*NS)
  WSALLOC(float, entry,  (size_t)NCHK*NS)
  WSALLOC(bf16,  Winbf,  (size_t)3*II*DD)   // 2.36 MB
  WSALLOC(bf16,  Woutbf, (size_t)DD*II)     // 0.79 MB
  WSALLOC(bf16,  Bmhi,   (size_t)NS*II)
  WSALLOC(bf16,  Bmlo,   (size_t)NS*II)
  WSALLOC(float, Apow,   13*256 + 16)
  WSALLOC(float, Etab,   (size_t)NT*256)    // 1 MB
  WSALLOC(float, Gtab,   (size_t)NT*256)    // 1 MB
  WSALLOC(float, dEtab,  (size_t)NT*256)    // 1 MB
  #undef WSALLOC

  prep_kernel  <<<1601, 256, 0, stream>>>(
      W_in, Wout, Bm, A, Winbf, Woutbf, Bmhi, Bmlo, dacc, Apow);
  etab_kernel  <<<NT, 64, 0, stream>>>(Apow, Etab, Gtab, dEtab);
  ln_kernel    <<<MT/4, 256, 0, stream>>>(x, ln_g, ln_b, hbf);
  gemm1_mfma   <<<dim3(2304), 256, 0, stream>>>(hbf, Winbf, databf, gatebf, dacc);
  convw_mfma   <<<MT/16, 256, 0, stream>>>(databf, conv_w, Bmhi, Bmlo, w_all);
  scan1_kernel <<<NCHK, 256, 0, stream>>>(Etab, Gtab, dEtab, dacc, w_all, c_all, Pbuf, qbuf);
  scan2_kernel <<<BB, 64, 0, stream>>>(Pbuf, qbuf, entry);
  scan3sel_kernel<<<NCHK, 256, 0, stream>>>(Etab, dEtab, dacc, c_all, entry, Cm, gatebf, databf);
  gemm2_mfma   <<<dim3(512), 256, 0, stream>>>(databf, Woutbf, x, out);
}